// Round 2
// baseline (484.944 us; speedup 1.0000x reference)
//
#include <hip/hip_runtime.h>
#include <math.h>

#define NMAT 8192
#define GT   128                    // NMAT / 64 tiles per dim
#define NPAIRS (GT * (GT + 1) / 2)  // 8256

typedef float f4 __attribute__((ext_vector_type(4)));

// Module-scope scratch: d_ws proved too small (round 1 corrupted the
// harness's pristine input copy via OOB writes). These are allocated at
// library load and fully re-initialized on every call.
__device__ __align__(16) float g_rowsum[NMAT];
__device__ __align__(16) float g_dvec[NMAT];

// ---------------------------------------------------------------------------
// Triangular pair decode: linear p -> (bi, bj), bi <= bj.
__device__ __forceinline__ int tri_off(int b) {
    return b * GT - ((b * (b - 1)) >> 1);
}

__device__ __forceinline__ void decode_pair(int p, int& bi, int& bj) {
    double dp = (double)p;
    double t = 2.0 * GT + 1.0;
    int b = (int)((t - sqrt(t * t - 8.0 * dp)) * 0.5);
    if (b < 0) b = 0;
    if (b > GT - 1) b = GT - 1;
    while (b + 1 < GT && tri_off(b + 1) <= p) ++b;
    while (b > 0 && tri_off(b) > p) --b;
    bi = b;
    bj = b + (p - tri_off(b));
}

// ---------------------------------------------------------------------------
__global__ void init_rowsum() {
    int i = blockIdx.x * blockDim.x + threadIdx.x;
    if (i < NMAT) g_rowsum[i] = 1.0f;  // self-loop contribution (+I)
}

__global__ void calc_d() {
    int i = blockIdx.x * blockDim.x + threadIdx.x;
    if (i < NMAT) {
        float s = g_rowsum[i];
        g_dvec[i] = (s > 0.0f) ? (float)(1.0 / sqrt((double)s)) : 0.0f;
    }
}

// ---------------------------------------------------------------------------
// Pass 1: rowsum[i] += sum_j max(A[i,j], A[j,i]) over tile pair (bi,bj).
__global__ __launch_bounds__(256) void pass1_rowsum(const float* __restrict__ A) {
    __shared__ float Yl[64][65];
    __shared__ float colbuf[4][64];

    int bi, bj;
    decode_pair((int)blockIdx.x, bi, bj);

    const int tid   = threadIdx.x;
    const int l16   = tid & 15;
    const int g16   = tid >> 4;
    const int cbase = l16 * 4;
    const int lane  = tid & 63;
    const int w     = tid >> 6;

    const float* Ybase = A + (size_t)(bj * 64) * NMAT + bi * 64;
    const float* Xbase = A + (size_t)(bi * 64) * NMAT + bj * 64;

    // Prefetch BOTH tiles into registers before any barrier (8 outstanding
    // 16B loads per thread — overlaps both tiles' HBM latency).
    f4 y[4], x[4];
    for (int k = 0; k < 4; ++k) {
        int q = k * 16 + g16;
        y[k] = *(const f4*)(Ybase + (size_t)q * NMAT + cbase);
    }
    for (int k = 0; k < 4; ++k) {
        int r = k * 16 + g16;
        x[k] = *(const f4*)(Xbase + (size_t)r * NMAT + cbase);
    }

    for (int k = 0; k < 4; ++k) {
        int q = k * 16 + g16;
        Yl[q][cbase + 0] = y[k].x;
        Yl[q][cbase + 1] = y[k].y;
        Yl[q][cbase + 2] = y[k].z;
        Yl[q][cbase + 3] = y[k].w;
    }
    __syncthreads();

    float cs0 = 0.f, cs1 = 0.f, cs2 = 0.f, cs3 = 0.f;

    for (int k = 0; k < 4; ++k) {
        int r = k * 16 + g16;
        float m0 = fmaxf(x[k].x, Yl[cbase + 0][r]);
        float m1 = fmaxf(x[k].y, Yl[cbase + 1][r]);
        float m2 = fmaxf(x[k].z, Yl[cbase + 2][r]);
        float m3 = fmaxf(x[k].w, Yl[cbase + 3][r]);
        cs0 += m0; cs1 += m1; cs2 += m2; cs3 += m3;
        float rt = (m0 + m1) + (m2 + m3);
        rt += __shfl_xor(rt, 1);
        rt += __shfl_xor(rt, 2);
        rt += __shfl_xor(rt, 4);
        rt += __shfl_xor(rt, 8);
        if (l16 == 0) atomicAdd(&g_rowsum[bi * 64 + r], rt);
    }

    if (bi != bj) {
        cs0 += __shfl_xor(cs0, 16); cs0 += __shfl_xor(cs0, 32);
        cs1 += __shfl_xor(cs1, 16); cs1 += __shfl_xor(cs1, 32);
        cs2 += __shfl_xor(cs2, 16); cs2 += __shfl_xor(cs2, 32);
        cs3 += __shfl_xor(cs3, 16); cs3 += __shfl_xor(cs3, 32);
        if (lane < 16) {
            colbuf[w][lane * 4 + 0] = cs0;
            colbuf[w][lane * 4 + 1] = cs1;
            colbuf[w][lane * 4 + 2] = cs2;
            colbuf[w][lane * 4 + 3] = cs3;
        }
        __syncthreads();
        if (tid < 64) {
            float t = (colbuf[0][tid] + colbuf[1][tid]) +
                      (colbuf[2][tid] + colbuf[3][tid]);
            atomicAdd(&g_rowsum[bj * 64 + tid], t);
        }
    }
}

// ---------------------------------------------------------------------------
// Pass 2: out[i,j] = d[i]*d[j]*(max(A[i,j],A[j,i]) + (i==j)).
// Block order REVERSED vs pass 1 so the tail of A (still resident in the
// 256 MiB Infinity Cache after pass 1) is re-read first -> LLC hits.
// Non-temporal stores keep the 268 MB of output writes from evicting A.
__global__ __launch_bounds__(256) void pass2_scale(const float* __restrict__ A,
                                                   float* __restrict__ out) {
    __shared__ float Yl[64][65];

    int bi, bj;
    decode_pair(NPAIRS - 1 - (int)blockIdx.x, bi, bj);

    const int tid   = threadIdx.x;
    const int l16   = tid & 15;
    const int g16   = tid >> 4;
    const int cbase = l16 * 4;

    const float* Ybase = A + (size_t)(bj * 64) * NMAT + bi * 64;
    const float* Xbase = A + (size_t)(bi * 64) * NMAT + bj * 64;

    f4 y[4], x[4];
    for (int k = 0; k < 4; ++k) {
        int q = k * 16 + g16;
        y[k] = *(const f4*)(Ybase + (size_t)q * NMAT + cbase);
    }
    for (int k = 0; k < 4; ++k) {
        int r = k * 16 + g16;
        x[k] = *(const f4*)(Xbase + (size_t)r * NMAT + cbase);
    }

    for (int k = 0; k < 4; ++k) {
        int q = k * 16 + g16;
        Yl[q][cbase + 0] = y[k].x;
        Yl[q][cbase + 1] = y[k].y;
        Yl[q][cbase + 2] = y[k].z;
        Yl[q][cbase + 3] = y[k].w;
    }
    __syncthreads();

    const f4 dj = *(const f4*)(g_dvec + bj * 64 + cbase);
    const bool diag = (bi == bj);

    for (int k = 0; k < 4; ++k) {
        int r = k * 16 + g16;
        float di = g_dvec[bi * 64 + r];
        float m0 = fmaxf(x[k].x, Yl[cbase + 0][r]);
        float m1 = fmaxf(x[k].y, Yl[cbase + 1][r]);
        float m2 = fmaxf(x[k].z, Yl[cbase + 2][r]);
        float m3 = fmaxf(x[k].w, Yl[cbase + 3][r]);
        if (diag) {
            if (r == cbase + 0) m0 += 1.0f;
            if (r == cbase + 1) m1 += 1.0f;
            if (r == cbase + 2) m2 += 1.0f;
            if (r == cbase + 3) m3 += 1.0f;
        }
        f4 v;
        v.x = di * dj.x * m0;
        v.y = di * dj.y * m1;
        v.z = di * dj.z * m2;
        v.w = di * dj.w * m3;
        __builtin_nontemporal_store(v, (f4*)(out + (size_t)(bi * 64 + r) * NMAT + bj * 64 + cbase));
        // Stash scaled values (each LDS slot owned by exactly one thread).
        Yl[cbase + 0][r] = v.x;
        Yl[cbase + 1][r] = v.y;
        Yl[cbase + 2][r] = v.z;
        Yl[cbase + 3][r] = v.w;
    }

    if (!diag) {
        __syncthreads();
        for (int k = 0; k < 4; ++k) {
            int q = k * 16 + g16;
            f4 v;
            v.x = Yl[q][cbase + 0];
            v.y = Yl[q][cbase + 1];
            v.z = Yl[q][cbase + 2];
            v.w = Yl[q][cbase + 3];
            __builtin_nontemporal_store(v, (f4*)(out + (size_t)(bj * 64 + q) * NMAT + bi * 64 + cbase));
        }
    }
}

// ---------------------------------------------------------------------------
extern "C" void kernel_launch(void* const* d_in, const int* in_sizes, int n_in,
                              void* d_out, int out_size, void* d_ws, size_t ws_size,
                              hipStream_t stream) {
    const float* A = (const float*)d_in[0];
    float* out     = (float*)d_out;

    init_rowsum<<<NMAT / 256, 256, 0, stream>>>();
    pass1_rowsum<<<NPAIRS, 256, 0, stream>>>(A);
    calc_d<<<NMAT / 256, 256, 0, stream>>>();
    pass2_scale<<<NPAIRS, 256, 0, stream>>>(A, out);
}